// Round 6
// baseline (29.776 us; speedup 1.0000x reference)
//
#include <hip/hip_runtime.h>
#include <cmath>

#define NN 1024
#define FF 512
#define HH 64
#define NPAIRS 528   // 32*33/2 unordered pairs of 32-row tiles

// ---------------------------------------------------------------------------
// k1: h = relu(x@W1 + b1) @ W2 + b2 ; ei = h@Wa1[:H] ; ejb = h@Wa1[H:] + ba1
// 256 blocks x 512 threads, 4 rows per block, 8-way k-split.
// Block 0 tid 0 zeroes the arrival counter for k2 (plain store; visible at
// the kernel boundary).
// ---------------------------------------------------------------------------
__global__ __launch_bounds__(512, 4) void k1_transform(
    const float* __restrict__ x, const float* __restrict__ W1,
    const float* __restrict__ b1, const float* __restrict__ W2,
    const float* __restrict__ b2, const float* __restrict__ Wa1,
    const float* __restrict__ ba1,
    float* __restrict__ ei, float* __restrict__ ejb,
    int* __restrict__ counter)
{
    __shared__ float xs[4][516];       // 516%32==4 -> bank spread
    __shared__ float ts[4][68];
    __shared__ float hs[4][68];
    __shared__ float pp[8][4][68];     // k-split partials
    const int tid = threadIdx.x;
    const int row0 = blockIdx.x * 4;

    if (blockIdx.x == 0 && tid == 0) *counter = 0;

    // stage x tile [4][512]: 512 float4, one per thread
    {
        int r = tid >> 7;
        int cc = (tid & 127) << 2;
        *reinterpret_cast<float4*>(&xs[r][cc]) =
            *reinterpret_cast<const float4*>(x + (row0 + r) * FF + cc);
    }
    __syncthreads();

    const int ks = tid >> 6;          // 0..7  k-split eighth
    const int r  = (tid >> 4) & 3;    // row 0..3
    const int cg = (tid & 15) << 2;   // col group of 4

    // GEMM1 partial: k in [ks*64, ks*64+64)  (16 iters)
    {
        float4 acc = make_float4(0.f, 0.f, 0.f, 0.f);
        const int k0 = ks * 64;
        #pragma unroll 4
        for (int k = k0; k < k0 + 64; k += 4) {
            float4 a  = *reinterpret_cast<const float4*>(&xs[r][k]);
            float4 w0 = *reinterpret_cast<const float4*>(W1 + (k + 0) * HH + cg);
            float4 w1 = *reinterpret_cast<const float4*>(W1 + (k + 1) * HH + cg);
            float4 w2 = *reinterpret_cast<const float4*>(W1 + (k + 2) * HH + cg);
            float4 w3 = *reinterpret_cast<const float4*>(W1 + (k + 3) * HH + cg);
            acc.x += a.x * w0.x + a.y * w1.x + a.z * w2.x + a.w * w3.x;
            acc.y += a.x * w0.y + a.y * w1.y + a.z * w2.y + a.w * w3.y;
            acc.z += a.x * w0.z + a.y * w1.z + a.z * w2.z + a.w * w3.z;
            acc.w += a.x * w0.w + a.y * w1.w + a.z * w2.w + a.w * w3.w;
        }
        *reinterpret_cast<float4*>(&pp[ks][r][cg]) = acc;
    }
    __syncthreads();
    if (ks == 0) {
        float4 s0 = *reinterpret_cast<const float4*>(&pp[0][r][cg]);
        #pragma unroll
        for (int q = 1; q < 8; ++q) {
            float4 p = *reinterpret_cast<const float4*>(&pp[q][r][cg]);
            s0.x += p.x; s0.y += p.y; s0.z += p.z; s0.w += p.w;
        }
        float4 bv = *reinterpret_cast<const float4*>(b1 + cg);
        float4 t;
        t.x = fmaxf(s0.x + bv.x, 0.f);
        t.y = fmaxf(s0.y + bv.y, 0.f);
        t.z = fmaxf(s0.z + bv.z, 0.f);
        t.w = fmaxf(s0.w + bv.w, 0.f);
        *reinterpret_cast<float4*>(&ts[r][cg]) = t;
    }
    __syncthreads();

    // GEMM2 partial: k in [ks*8, ks*8+8)  (2 iters)
    {
        float4 acc = make_float4(0.f, 0.f, 0.f, 0.f);
        const int k0 = ks * 8;
        #pragma unroll
        for (int k = k0; k < k0 + 8; k += 4) {
            float4 a  = *reinterpret_cast<const float4*>(&ts[r][k]);
            float4 w0 = *reinterpret_cast<const float4*>(W2 + (k + 0) * HH + cg);
            float4 w1 = *reinterpret_cast<const float4*>(W2 + (k + 1) * HH + cg);
            float4 w2 = *reinterpret_cast<const float4*>(W2 + (k + 2) * HH + cg);
            float4 w3 = *reinterpret_cast<const float4*>(W2 + (k + 3) * HH + cg);
            acc.x += a.x * w0.x + a.y * w1.x + a.z * w2.x + a.w * w3.x;
            acc.y += a.x * w0.y + a.y * w1.y + a.z * w2.y + a.w * w3.y;
            acc.z += a.x * w0.z + a.y * w1.z + a.z * w2.z + a.w * w3.z;
            acc.w += a.x * w0.w + a.y * w1.w + a.z * w2.w + a.w * w3.w;
        }
        *reinterpret_cast<float4*>(&pp[ks][r][cg]) = acc;
    }
    __syncthreads();
    if (ks == 0) {
        float4 s0 = *reinterpret_cast<const float4*>(&pp[0][r][cg]);
        #pragma unroll
        for (int q = 1; q < 8; ++q) {
            float4 p = *reinterpret_cast<const float4*>(&pp[q][r][cg]);
            s0.x += p.x; s0.y += p.y; s0.z += p.z; s0.w += p.w;
        }
        float4 bv = *reinterpret_cast<const float4*>(b2 + cg);
        float4 h;
        h.x = s0.x + bv.x; h.y = s0.y + bv.y;
        h.z = s0.z + bv.z; h.w = s0.w + bv.w;
        *reinterpret_cast<float4*>(&hs[r][cg]) = h;
    }
    __syncthreads();

    // GEMM3: ks>>2 selects ei (0) / ejb (1); ks&3 selects k-quarter of 16
    {
        const float* Wb = Wa1 + (ks >> 2) * HH * HH;
        float4 acc = make_float4(0.f, 0.f, 0.f, 0.f);
        const int k0 = (ks & 3) * 16;
        #pragma unroll
        for (int k = k0; k < k0 + 16; k += 4) {
            float4 a  = *reinterpret_cast<const float4*>(&hs[r][k]);
            float4 w0 = *reinterpret_cast<const float4*>(Wb + (k + 0) * HH + cg);
            float4 w1 = *reinterpret_cast<const float4*>(Wb + (k + 1) * HH + cg);
            float4 w2 = *reinterpret_cast<const float4*>(Wb + (k + 2) * HH + cg);
            float4 w3 = *reinterpret_cast<const float4*>(Wb + (k + 3) * HH + cg);
            acc.x += a.x * w0.x + a.y * w1.x + a.z * w2.x + a.w * w3.x;
            acc.y += a.x * w0.y + a.y * w1.y + a.z * w2.y + a.w * w3.y;
            acc.z += a.x * w0.z + a.y * w1.z + a.z * w2.z + a.w * w3.z;
            acc.w += a.x * w0.w + a.y * w1.w + a.z * w2.w + a.w * w3.w;
        }
        *reinterpret_cast<float4*>(&pp[ks][r][cg]) = acc;
    }
    __syncthreads();
    if (ks == 0) {
        float4 s0 = *reinterpret_cast<const float4*>(&pp[0][r][cg]);
        #pragma unroll
        for (int q = 1; q < 4; ++q) {
            float4 p = *reinterpret_cast<const float4*>(&pp[q][r][cg]);
            s0.x += p.x; s0.y += p.y; s0.z += p.z; s0.w += p.w;
        }
        *reinterpret_cast<float4*>(ei + (row0 + r) * HH + cg) = s0;
    } else if (ks == 4) {
        float4 s0 = *reinterpret_cast<const float4*>(&pp[4][r][cg]);
        #pragma unroll
        for (int q = 5; q < 8; ++q) {
            float4 p = *reinterpret_cast<const float4*>(&pp[q][r][cg]);
            s0.x += p.x; s0.y += p.y; s0.z += p.z; s0.w += p.w;
        }
        float4 bv = *reinterpret_cast<const float4*>(ba1 + cg);
        s0.x += bv.x; s0.y += bv.y; s0.z += bv.z; s0.w += bv.w;
        *reinterpret_cast<float4*>(ejb + (row0 + r) * HH + cg) = s0;
    }
}

// ---------------------------------------------------------------------------
// k2_pair: per unordered 32-tile pair (I<=J): compute BOTH raw directions
// in-register, symmetrize + sigmoid once, write both mirrored outputs.
// Fused loss: per-block partial via atomicExch (device-coherent), arrival
// counter via atomicAdd; NO __threadfence (only a wave-local vmcnt wait).
// Last-arriving block tree-sums 528 partials in fixed slot order ->
// bitwise-deterministic loss.  528 blocks x 256 threads.
// ---------------------------------------------------------------------------
__global__ __launch_bounds__(256, 4) void k2_pair(
    const float* __restrict__ ei, const float* __restrict__ ejb,
    const float* __restrict__ wa2, const float* __restrict__ ba2,
    const float* __restrict__ temp,
    float* __restrict__ out, float* __restrict__ partials,
    int* __restrict__ counter, float* __restrict__ out_loss)
{
    __shared__ float stg[4][32][68];   // 0:ei_I 1:ei_J 2:ejb_I 3:ejb_J
    __shared__ float T[32][33];        // adj transpose bounce
    __shared__ float wl[64];
    __shared__ float wsum[4];
    __shared__ int lastFlag;
    const int tid = threadIdx.x;

    // decode unordered pair (I<=J), I,J in [0,32)
    int I = 0, rem = blockIdx.x, rl = 32;
    while (rem >= rl) { rem -= rl; ++I; --rl; }
    const int J = I + rem;
    const int iBase = I * 32, jBase = J * 32;
    const bool off = (I != J);

    // stage 4 tiles of 32 rows x 64 cols (512 float4 each, 2 per thread)
    {
        const int rr = tid >> 4;          // 0..15
        const int cq = (tid & 15) << 2;
        const float* s0 = ei  + iBase * HH;
        const float* s1 = ei  + jBase * HH;
        const float* s2 = ejb + iBase * HH;
        const float* s3 = ejb + jBase * HH;
        #pragma unroll
        for (int l = 0; l < 2; ++l) {
            int r = rr + 16 * l;
            *reinterpret_cast<float4*>(&stg[0][r][cq]) =
                *reinterpret_cast<const float4*>(s0 + r * HH + cq);
            *reinterpret_cast<float4*>(&stg[1][r][cq]) =
                *reinterpret_cast<const float4*>(s1 + r * HH + cq);
            *reinterpret_cast<float4*>(&stg[2][r][cq]) =
                *reinterpret_cast<const float4*>(s2 + r * HH + cq);
            *reinterpret_cast<float4*>(&stg[3][r][cq]) =
                *reinterpret_cast<const float4*>(s3 + r * HH + cq);
        }
    }
    if (tid < 16) {
        *reinterpret_cast<float4*>(&wl[tid * 4]) =
            *reinterpret_cast<const float4*>(wa2 + tid * 4);
    }
    __syncthreads();

    const int c  = tid & 31;   // col within tile (per-lane)
    const int r0 = tid >> 5;   // 0..7 -> rows r0+8m (broadcast within half-wave)

    float d1[4] = {0.f, 0.f, 0.f, 0.f};   // S_raw[iBase+row][jBase+c]
    float d2[4] = {0.f, 0.f, 0.f, 0.f};   // S_raw[jBase+c][iBase+row]

    #pragma unroll 4
    for (int h = 0; h < HH; h += 4) {
        float4 w  = *reinterpret_cast<const float4*>(&wl[h]);
        {
            float4 Bj = *reinterpret_cast<const float4*>(&stg[3][c][h]);  // ejb_J[c]
            #pragma unroll
            for (int m = 0; m < 4; ++m) {
                float4 Ai = *reinterpret_cast<const float4*>(&stg[0][r0 + 8 * m][h]);
                d1[m] += fmaxf(Ai.x + Bj.x, 0.f) * w.x
                       + fmaxf(Ai.y + Bj.y, 0.f) * w.y
                       + fmaxf(Ai.z + Bj.z, 0.f) * w.z
                       + fmaxf(Ai.w + Bj.w, 0.f) * w.w;
            }
        }
        {
            float4 Ej = *reinterpret_cast<const float4*>(&stg[1][c][h]);  // ei_J[c]
            #pragma unroll
            for (int m = 0; m < 4; ++m) {
                float4 Bi = *reinterpret_cast<const float4*>(&stg[2][r0 + 8 * m][h]);
                d2[m] += fmaxf(Ej.x + Bi.x, 0.f) * w.x
                       + fmaxf(Ej.y + Bi.y, 0.f) * w.y
                       + fmaxf(Ej.z + Bi.z, 0.f) * w.z
                       + fmaxf(Ej.w + Bi.w, 0.f) * w.w;
            }
        }
    }

    const float t = fminf(fmaxf(temp[0], 0.1f), 5.0f);
    const float invt = 1.0f / t;
    const float bb = ba2[0];

    float adj4[4];
    float lsum = 0.f;
    #pragma unroll
    for (int m = 0; m < 4; ++m) {
        const int row = r0 + 8 * m;
        float v = (0.5f * (d1[m] + d2[m]) + bb) * invt;
        float adj = 1.0f / (1.0f + __expf(-v));
        adj4[m] = adj;
        out[(iBase + row) * NN + jBase + c] = adj;   // own position, coalesced
        lsum += adj;
    }

    if (off) {
        // mirrored tile (J,I) via LDS transpose bounce
        #pragma unroll
        for (int m = 0; m < 4; ++m) T[c][r0 + 8 * m] = adj4[m];
        __syncthreads();
        #pragma unroll
        for (int m = 0; m < 4; ++m) {
            const int rr = r0 + 8 * m;
            out[(jBase + rr) * NN + iBase + c] = T[rr][c];
        }
        lsum *= 2.0f;   // value counted at both mirrored positions
    }

    // deterministic per-block partial: fixed shuffle tree + fixed wave order
    float w = lsum;
    #pragma unroll
    for (int o = 32; o > 0; o >>= 1) w += __shfl_down(w, o);
    if ((tid & 63) == 0) wsum[tid >> 6] = w;
    __syncthreads();
    if (tid == 0) {
        float tot = (wsum[0] + wsum[1]) + (wsum[2] + wsum[3]);
        // device-coherent publish (atomic op -> coherent point, bypasses
        // non-coherent XCD caching). NO __threadfence: only wait for MY
        // exch to complete (vmcnt drain) before announcing arrival.
        atomicExch(&partials[blockIdx.x], tot);
        __threadfence_block();                 // s_waitcnt, no L2 writeback
        int old = atomicAdd(counter, 1);
        lastFlag = (old == NPAIRS - 1);
    }
    __syncthreads();

    if (lastFlag) {
        // last arriver: all 527 other blocks' exch ops committed to the
        // coherent point before their counter increments -> atomic reads
        // below observe them. Fixed-order tree -> bitwise deterministic.
        float v = atomicAdd(&partials[tid], 0.0f)
                + atomicAdd(&partials[tid + 256], 0.0f);
        if (tid < 16) v += atomicAdd(&partials[tid + 512], 0.0f);
        #pragma unroll
        for (int o = 32; o > 0; o >>= 1) v += __shfl_down(v, o);
        if ((tid & 63) == 0) wsum[tid >> 6] = v;
        __syncthreads();
        if (tid == 0) {
            float tot = (wsum[0] + wsum[1]) + (wsum[2] + wsum[3]);
            *out_loss = 0.01f * tot / (float)(NN * NN);
        }
    }
}

extern "C" void kernel_launch(void* const* d_in, const int* in_sizes, int n_in,
                              void* d_out, int out_size, void* d_ws, size_t ws_size,
                              hipStream_t stream)
{
    const float* x    = (const float*)d_in[0];
    const float* W1   = (const float*)d_in[1];
    const float* b1   = (const float*)d_in[2];
    const float* W2   = (const float*)d_in[3];
    const float* b2   = (const float*)d_in[4];
    const float* Wa1  = (const float*)d_in[5];
    const float* ba1  = (const float*)d_in[6];
    const float* wa2  = (const float*)d_in[7];
    const float* ba2  = (const float*)d_in[8];
    const float* temp = (const float*)d_in[9];
    float* out = (float*)d_out;

    float* ei    = (float*)d_ws;            // N*H floats
    float* ejb   = ei + NN * HH;            // N*H floats
    float* parts = ejb + NN * HH;           // NPAIRS floats
    int*   ctr   = (int*)(parts + NPAIRS);  // arrival counter

    k1_transform<<<NN / 4, 512, 0, stream>>>(x, W1, b1, W2, b2, Wa1, ba1, ei, ejb, ctr);
    k2_pair<<<NPAIRS, 256, 0, stream>>>(ei, ejb, wa2, ba2, temp, out, parts, ctr,
                                        out + NN * NN);
}

// Round 7
// 27.846 us; speedup vs baseline: 1.0693x; 1.0693x over previous
//
#include <hip/hip_runtime.h>
#include <cmath>

#define NN 1024
#define FF 512
#define HH 64
#define NPAIRS 528   // 32*33/2 unordered pairs of 32-row tiles

// ---------------------------------------------------------------------------
// k1: h = relu(x@W1 + b1) @ W2 + b2 ; ei = h@Wa1[:H] ; ejb = h@Wa1[H:] + ba1
// 256 blocks x 1024 threads (16 waves/CU = 4 waves/SIMD), 4 rows per block,
// 16-way k-split: per-thread GEMM1 chain is only 8 independent groups of 4
// W1 loads -> latency-tolerant.
// ks = tid>>6 (0..15), r = (tid>>4)&3, cg = (tid&15)*4.
// ---------------------------------------------------------------------------
__global__ __launch_bounds__(1024, 4) void k1_transform(
    const float* __restrict__ x, const float* __restrict__ W1,
    const float* __restrict__ b1, const float* __restrict__ W2,
    const float* __restrict__ b2, const float* __restrict__ Wa1,
    const float* __restrict__ ba1,
    float* __restrict__ ei, float* __restrict__ ejb)
{
    __shared__ float xs[4][516];       // 516%32==4 -> bank spread
    __shared__ float ts[4][68];
    __shared__ float hs[4][68];
    __shared__ float pp[16][4][68];    // k-split partials
    const int tid = threadIdx.x;
    const int row0 = blockIdx.x * 4;

    // stage x tile [4][512]: 512 float4, first 512 threads load one each
    if (tid < 512) {
        int r = tid >> 7;
        int cc = (tid & 127) << 2;
        *reinterpret_cast<float4*>(&xs[r][cc]) =
            *reinterpret_cast<const float4*>(x + (row0 + r) * FF + cc);
    }
    __syncthreads();

    const int ks = tid >> 6;          // 0..15  k-split sixteenth
    const int r  = (tid >> 4) & 3;    // row 0..3
    const int cg = (tid & 15) << 2;   // col group of 4

    // GEMM1 partial: k in [ks*32, ks*32+32)  (8 iters)
    {
        float4 acc = make_float4(0.f, 0.f, 0.f, 0.f);
        const int k0 = ks * 32;
        #pragma unroll 4
        for (int k = k0; k < k0 + 32; k += 4) {
            float4 a  = *reinterpret_cast<const float4*>(&xs[r][k]);
            float4 w0 = *reinterpret_cast<const float4*>(W1 + (k + 0) * HH + cg);
            float4 w1 = *reinterpret_cast<const float4*>(W1 + (k + 1) * HH + cg);
            float4 w2 = *reinterpret_cast<const float4*>(W1 + (k + 2) * HH + cg);
            float4 w3 = *reinterpret_cast<const float4*>(W1 + (k + 3) * HH + cg);
            acc.x += a.x * w0.x + a.y * w1.x + a.z * w2.x + a.w * w3.x;
            acc.y += a.x * w0.y + a.y * w1.y + a.z * w2.y + a.w * w3.y;
            acc.z += a.x * w0.z + a.y * w1.z + a.z * w2.z + a.w * w3.z;
            acc.w += a.x * w0.w + a.y * w1.w + a.z * w2.w + a.w * w3.w;
        }
        *reinterpret_cast<float4*>(&pp[ks][r][cg]) = acc;
    }
    __syncthreads();
    if (ks == 0) {
        float4 s0 = *reinterpret_cast<const float4*>(&pp[0][r][cg]);
        #pragma unroll
        for (int q = 1; q < 16; ++q) {
            float4 p = *reinterpret_cast<const float4*>(&pp[q][r][cg]);
            s0.x += p.x; s0.y += p.y; s0.z += p.z; s0.w += p.w;
        }
        float4 bv = *reinterpret_cast<const float4*>(b1 + cg);
        float4 t;
        t.x = fmaxf(s0.x + bv.x, 0.f);
        t.y = fmaxf(s0.y + bv.y, 0.f);
        t.z = fmaxf(s0.z + bv.z, 0.f);
        t.w = fmaxf(s0.w + bv.w, 0.f);
        *reinterpret_cast<float4*>(&ts[r][cg]) = t;
    }
    __syncthreads();

    // GEMM2 partial: k = ks*4 (1 iter of 4)
    {
        float4 acc = make_float4(0.f, 0.f, 0.f, 0.f);
        const int k = ks * 4;
        float4 a  = *reinterpret_cast<const float4*>(&ts[r][k]);
        float4 w0 = *reinterpret_cast<const float4*>(W2 + (k + 0) * HH + cg);
        float4 w1 = *reinterpret_cast<const float4*>(W2 + (k + 1) * HH + cg);
        float4 w2 = *reinterpret_cast<const float4*>(W2 + (k + 2) * HH + cg);
        float4 w3 = *reinterpret_cast<const float4*>(W2 + (k + 3) * HH + cg);
        acc.x += a.x * w0.x + a.y * w1.x + a.z * w2.x + a.w * w3.x;
        acc.y += a.x * w0.y + a.y * w1.y + a.z * w2.y + a.w * w3.y;
        acc.z += a.x * w0.z + a.y * w1.z + a.z * w2.z + a.w * w3.z;
        acc.w += a.x * w0.w + a.y * w1.w + a.z * w2.w + a.w * w3.w;
        *reinterpret_cast<float4*>(&pp[ks][r][cg]) = acc;
    }
    __syncthreads();
    if (ks == 0) {
        float4 s0 = *reinterpret_cast<const float4*>(&pp[0][r][cg]);
        #pragma unroll
        for (int q = 1; q < 16; ++q) {
            float4 p = *reinterpret_cast<const float4*>(&pp[q][r][cg]);
            s0.x += p.x; s0.y += p.y; s0.z += p.z; s0.w += p.w;
        }
        float4 bv = *reinterpret_cast<const float4*>(b2 + cg);
        float4 h;
        h.x = s0.x + bv.x; h.y = s0.y + bv.y;
        h.z = s0.z + bv.z; h.w = s0.w + bv.w;
        *reinterpret_cast<float4*>(&hs[r][cg]) = h;
    }
    __syncthreads();

    // GEMM3: ks>>3 selects ei (0) / ejb (1); ks&7 selects k-eighth of 8
    {
        const float* Wb = Wa1 + (ks >> 3) * HH * HH;
        float4 acc = make_float4(0.f, 0.f, 0.f, 0.f);
        const int k0 = (ks & 7) * 8;
        #pragma unroll
        for (int k = k0; k < k0 + 8; k += 4) {
            float4 a  = *reinterpret_cast<const float4*>(&hs[r][k]);
            float4 w0 = *reinterpret_cast<const float4*>(Wb + (k + 0) * HH + cg);
            float4 w1 = *reinterpret_cast<const float4*>(Wb + (k + 1) * HH + cg);
            float4 w2 = *reinterpret_cast<const float4*>(Wb + (k + 2) * HH + cg);
            float4 w3 = *reinterpret_cast<const float4*>(Wb + (k + 3) * HH + cg);
            acc.x += a.x * w0.x + a.y * w1.x + a.z * w2.x + a.w * w3.x;
            acc.y += a.x * w0.y + a.y * w1.y + a.z * w2.y + a.w * w3.y;
            acc.z += a.x * w0.z + a.y * w1.z + a.z * w2.z + a.w * w3.z;
            acc.w += a.x * w0.w + a.y * w1.w + a.z * w2.w + a.w * w3.w;
        }
        *reinterpret_cast<float4*>(&pp[ks][r][cg]) = acc;
    }
    __syncthreads();
    if (ks == 0) {
        float4 s0 = *reinterpret_cast<const float4*>(&pp[0][r][cg]);
        #pragma unroll
        for (int q = 1; q < 8; ++q) {
            float4 p = *reinterpret_cast<const float4*>(&pp[q][r][cg]);
            s0.x += p.x; s0.y += p.y; s0.z += p.z; s0.w += p.w;
        }
        *reinterpret_cast<float4*>(ei + (row0 + r) * HH + cg) = s0;
    } else if (ks == 8) {
        float4 s0 = *reinterpret_cast<const float4*>(&pp[8][r][cg]);
        #pragma unroll
        for (int q = 9; q < 16; ++q) {
            float4 p = *reinterpret_cast<const float4*>(&pp[q][r][cg]);
            s0.x += p.x; s0.y += p.y; s0.z += p.z; s0.w += p.w;
        }
        float4 bv = *reinterpret_cast<const float4*>(ba1 + cg);
        s0.x += bv.x; s0.y += bv.y; s0.z += bv.z; s0.w += bv.w;
        *reinterpret_cast<float4*>(ejb + (row0 + r) * HH + cg) = s0;
    }
}

// ---------------------------------------------------------------------------
// k2_pair: per unordered 32-tile pair (I<=J): compute BOTH raw directions
// in-register, symmetrize + sigmoid once, write both mirrored outputs
// (transpose bounce via LDS). Plain-store per-block partial sums.
// 528 blocks x 256 threads.  (R5 version — atomics regressed, reverted.)
// ---------------------------------------------------------------------------
__global__ __launch_bounds__(256, 4) void k2_pair(
    const float* __restrict__ ei, const float* __restrict__ ejb,
    const float* __restrict__ wa2, const float* __restrict__ ba2,
    const float* __restrict__ temp,
    float* __restrict__ out, float* __restrict__ partials)
{
    __shared__ float stg[4][32][68];   // 0:ei_I 1:ei_J 2:ejb_I 3:ejb_J
    __shared__ float T[32][33];        // adj transpose bounce
    __shared__ float wl[64];
    __shared__ float wsum[4];
    const int tid = threadIdx.x;

    // decode unordered pair (I<=J), I,J in [0,32)
    int I = 0, rem = blockIdx.x, rl = 32;
    while (rem >= rl) { rem -= rl; ++I; --rl; }
    const int J = I + rem;
    const int iBase = I * 32, jBase = J * 32;
    const bool off = (I != J);

    // stage 4 tiles of 32 rows x 64 cols (512 float4 each, 2 per thread)
    {
        const int rr = tid >> 4;          // 0..15
        const int cq = (tid & 15) << 2;
        const float* s0 = ei  + iBase * HH;
        const float* s1 = ei  + jBase * HH;
        const float* s2 = ejb + iBase * HH;
        const float* s3 = ejb + jBase * HH;
        #pragma unroll
        for (int l = 0; l < 2; ++l) {
            int r = rr + 16 * l;
            *reinterpret_cast<float4*>(&stg[0][r][cq]) =
                *reinterpret_cast<const float4*>(s0 + r * HH + cq);
            *reinterpret_cast<float4*>(&stg[1][r][cq]) =
                *reinterpret_cast<const float4*>(s1 + r * HH + cq);
            *reinterpret_cast<float4*>(&stg[2][r][cq]) =
                *reinterpret_cast<const float4*>(s2 + r * HH + cq);
            *reinterpret_cast<float4*>(&stg[3][r][cq]) =
                *reinterpret_cast<const float4*>(s3 + r * HH + cq);
        }
    }
    if (tid < 16) {
        *reinterpret_cast<float4*>(&wl[tid * 4]) =
            *reinterpret_cast<const float4*>(wa2 + tid * 4);
    }
    __syncthreads();

    const int c  = tid & 31;   // col within tile (per-lane)
    const int r0 = tid >> 5;   // 0..7 -> rows r0+8m (broadcast within half-wave)

    float d1[4] = {0.f, 0.f, 0.f, 0.f};   // S_raw[iBase+row][jBase+c]
    float d2[4] = {0.f, 0.f, 0.f, 0.f};   // S_raw[jBase+c][iBase+row]

    #pragma unroll 4
    for (int h = 0; h < HH; h += 4) {
        float4 w  = *reinterpret_cast<const float4*>(&wl[h]);
        {
            float4 Bj = *reinterpret_cast<const float4*>(&stg[3][c][h]);  // ejb_J[c]
            #pragma unroll
            for (int m = 0; m < 4; ++m) {
                float4 Ai = *reinterpret_cast<const float4*>(&stg[0][r0 + 8 * m][h]);
                d1[m] += fmaxf(Ai.x + Bj.x, 0.f) * w.x
                       + fmaxf(Ai.y + Bj.y, 0.f) * w.y
                       + fmaxf(Ai.z + Bj.z, 0.f) * w.z
                       + fmaxf(Ai.w + Bj.w, 0.f) * w.w;
            }
        }
        {
            float4 Ej = *reinterpret_cast<const float4*>(&stg[1][c][h]);  // ei_J[c]
            #pragma unroll
            for (int m = 0; m < 4; ++m) {
                float4 Bi = *reinterpret_cast<const float4*>(&stg[2][r0 + 8 * m][h]);
                d2[m] += fmaxf(Ej.x + Bi.x, 0.f) * w.x
                       + fmaxf(Ej.y + Bi.y, 0.f) * w.y
                       + fmaxf(Ej.z + Bi.z, 0.f) * w.z
                       + fmaxf(Ej.w + Bi.w, 0.f) * w.w;
            }
        }
    }

    const float t = fminf(fmaxf(temp[0], 0.1f), 5.0f);
    const float invt = 1.0f / t;
    const float bb = ba2[0];

    float adj4[4];
    float lsum = 0.f;
    #pragma unroll
    for (int m = 0; m < 4; ++m) {
        const int row = r0 + 8 * m;
        float v = (0.5f * (d1[m] + d2[m]) + bb) * invt;
        float adj = 1.0f / (1.0f + __expf(-v));
        adj4[m] = adj;
        out[(iBase + row) * NN + jBase + c] = adj;   // own position, coalesced
        lsum += adj;
    }

    if (off) {
        // mirrored tile (J,I) via LDS transpose bounce
        #pragma unroll
        for (int m = 0; m < 4; ++m) T[c][r0 + 8 * m] = adj4[m];
        __syncthreads();
        #pragma unroll
        for (int m = 0; m < 4; ++m) {
            const int rr = r0 + 8 * m;
            out[(jBase + rr) * NN + iBase + c] = T[rr][c];
        }
        lsum *= 2.0f;   // value counted at both mirrored positions
    }

    // deterministic per-block partial: fixed shuffle tree + fixed wave order
    float w = lsum;
    #pragma unroll
    for (int o = 32; o > 0; o >>= 1) w += __shfl_down(w, o);
    if ((tid & 63) == 0) wsum[tid >> 6] = w;
    __syncthreads();
    if (tid == 0) {
        partials[blockIdx.x] = (wsum[0] + wsum[1]) + (wsum[2] + wsum[3]);
    }
}

// ---------------------------------------------------------------------------
// k3_reduce: 1 block, fixed-order deterministic tree over 528 partials.
// ---------------------------------------------------------------------------
__global__ __launch_bounds__(256) void k3_reduce(
    const float* __restrict__ partials, float* __restrict__ out_loss)
{
    __shared__ float wsum[4];
    const int tid = threadIdx.x;
    float v = partials[tid] + partials[tid + 256];
    if (tid < 16) v += partials[tid + 512];
    #pragma unroll
    for (int o = 32; o > 0; o >>= 1) v += __shfl_down(v, o);
    if ((tid & 63) == 0) wsum[tid >> 6] = v;
    __syncthreads();
    if (tid == 0) {
        float tot = (wsum[0] + wsum[1]) + (wsum[2] + wsum[3]);
        *out_loss = 0.01f * tot / (float)(NN * NN);
    }
}

extern "C" void kernel_launch(void* const* d_in, const int* in_sizes, int n_in,
                              void* d_out, int out_size, void* d_ws, size_t ws_size,
                              hipStream_t stream)
{
    const float* x    = (const float*)d_in[0];
    const float* W1   = (const float*)d_in[1];
    const float* b1   = (const float*)d_in[2];
    const float* W2   = (const float*)d_in[3];
    const float* b2   = (const float*)d_in[4];
    const float* Wa1  = (const float*)d_in[5];
    const float* ba1  = (const float*)d_in[6];
    const float* wa2  = (const float*)d_in[7];
    const float* ba2  = (const float*)d_in[8];
    const float* temp = (const float*)d_in[9];
    float* out = (float*)d_out;

    float* ei    = (float*)d_ws;            // N*H floats
    float* ejb   = ei + NN * HH;            // N*H floats
    float* parts = ejb + NN * HH;           // NPAIRS floats

    k1_transform<<<NN / 4, 1024, 0, stream>>>(x, W1, b1, W2, b2, Wa1, ba1, ei, ejb);
    k2_pair<<<NPAIRS, 256, 0, stream>>>(ei, ejb, wa2, ba2, temp, out, parts);
    k3_reduce<<<1, 256, 0, stream>>>(parts, out + NN * NN);
}

// Round 8
// 27.372 us; speedup vs baseline: 1.0878x; 1.0173x over previous
//
#include <hip/hip_runtime.h>
#include <cmath>

#define NN 1024
#define FF 512
#define HH 64
#define NPAIRS 528   // 32*33/2 unordered pairs of 32-row tiles (k3_sym)

// ---------------------------------------------------------------------------
// k1: h = relu(x@W1 + b1) @ W2 + b2 ; ei = h@Wa1[:H] ; ejb = h@Wa1[H:] + ba1
// 256 blocks x 1024 threads, 4 rows per block, 16-way k-split. (R7, at floor)
// ---------------------------------------------------------------------------
__global__ __launch_bounds__(1024, 4) void k1_transform(
    const float* __restrict__ x, const float* __restrict__ W1,
    const float* __restrict__ b1, const float* __restrict__ W2,
    const float* __restrict__ b2, const float* __restrict__ Wa1,
    const float* __restrict__ ba1,
    float* __restrict__ ei, float* __restrict__ ejb)
{
    __shared__ float xs[4][516];
    __shared__ float ts[4][68];
    __shared__ float hs[4][68];
    __shared__ float pp[16][4][68];
    const int tid = threadIdx.x;
    const int row0 = blockIdx.x * 4;

    if (tid < 512) {
        int r = tid >> 7;
        int cc = (tid & 127) << 2;
        *reinterpret_cast<float4*>(&xs[r][cc]) =
            *reinterpret_cast<const float4*>(x + (row0 + r) * FF + cc);
    }
    __syncthreads();

    const int ks = tid >> 6;
    const int r  = (tid >> 4) & 3;
    const int cg = (tid & 15) << 2;

    {
        float4 acc = make_float4(0.f, 0.f, 0.f, 0.f);
        const int k0 = ks * 32;
        #pragma unroll 4
        for (int k = k0; k < k0 + 32; k += 4) {
            float4 a  = *reinterpret_cast<const float4*>(&xs[r][k]);
            float4 w0 = *reinterpret_cast<const float4*>(W1 + (k + 0) * HH + cg);
            float4 w1 = *reinterpret_cast<const float4*>(W1 + (k + 1) * HH + cg);
            float4 w2 = *reinterpret_cast<const float4*>(W1 + (k + 2) * HH + cg);
            float4 w3 = *reinterpret_cast<const float4*>(W1 + (k + 3) * HH + cg);
            acc.x += a.x * w0.x + a.y * w1.x + a.z * w2.x + a.w * w3.x;
            acc.y += a.x * w0.y + a.y * w1.y + a.z * w2.y + a.w * w3.y;
            acc.z += a.x * w0.z + a.y * w1.z + a.z * w2.z + a.w * w3.z;
            acc.w += a.x * w0.w + a.y * w1.w + a.z * w2.w + a.w * w3.w;
        }
        *reinterpret_cast<float4*>(&pp[ks][r][cg]) = acc;
    }
    __syncthreads();
    if (ks == 0) {
        float4 s0 = *reinterpret_cast<const float4*>(&pp[0][r][cg]);
        #pragma unroll
        for (int q = 1; q < 16; ++q) {
            float4 p = *reinterpret_cast<const float4*>(&pp[q][r][cg]);
            s0.x += p.x; s0.y += p.y; s0.z += p.z; s0.w += p.w;
        }
        float4 bv = *reinterpret_cast<const float4*>(b1 + cg);
        float4 t;
        t.x = fmaxf(s0.x + bv.x, 0.f);
        t.y = fmaxf(s0.y + bv.y, 0.f);
        t.z = fmaxf(s0.z + bv.z, 0.f);
        t.w = fmaxf(s0.w + bv.w, 0.f);
        *reinterpret_cast<float4*>(&ts[r][cg]) = t;
    }
    __syncthreads();

    {
        float4 acc = make_float4(0.f, 0.f, 0.f, 0.f);
        const int k = ks * 4;
        float4 a  = *reinterpret_cast<const float4*>(&ts[r][k]);
        float4 w0 = *reinterpret_cast<const float4*>(W2 + (k + 0) * HH + cg);
        float4 w1 = *reinterpret_cast<const float4*>(W2 + (k + 1) * HH + cg);
        float4 w2 = *reinterpret_cast<const float4*>(W2 + (k + 2) * HH + cg);
        float4 w3 = *reinterpret_cast<const float4*>(W2 + (k + 3) * HH + cg);
        acc.x += a.x * w0.x + a.y * w1.x + a.z * w2.x + a.w * w3.x;
        acc.y += a.x * w0.y + a.y * w1.y + a.z * w2.y + a.w * w3.y;
        acc.z += a.x * w0.z + a.y * w1.z + a.z * w2.z + a.w * w3.z;
        acc.w += a.x * w0.w + a.y * w1.w + a.z * w2.w + a.w * w3.w;
        *reinterpret_cast<float4*>(&pp[ks][r][cg]) = acc;
    }
    __syncthreads();
    if (ks == 0) {
        float4 s0 = *reinterpret_cast<const float4*>(&pp[0][r][cg]);
        #pragma unroll
        for (int q = 1; q < 16; ++q) {
            float4 p = *reinterpret_cast<const float4*>(&pp[q][r][cg]);
            s0.x += p.x; s0.y += p.y; s0.z += p.z; s0.w += p.w;
        }
        float4 bv = *reinterpret_cast<const float4*>(b2 + cg);
        float4 h;
        h.x = s0.x + bv.x; h.y = s0.y + bv.y;
        h.z = s0.z + bv.z; h.w = s0.w + bv.w;
        *reinterpret_cast<float4*>(&hs[r][cg]) = h;
    }
    __syncthreads();

    {
        const float* Wb = Wa1 + (ks >> 3) * HH * HH;
        float4 acc = make_float4(0.f, 0.f, 0.f, 0.f);
        const int k0 = (ks & 7) * 8;
        #pragma unroll
        for (int k = k0; k < k0 + 8; k += 4) {
            float4 a  = *reinterpret_cast<const float4*>(&hs[r][k]);
            float4 w0 = *reinterpret_cast<const float4*>(Wb + (k + 0) * HH + cg);
            float4 w1 = *reinterpret_cast<const float4*>(Wb + (k + 1) * HH + cg);
            float4 w2 = *reinterpret_cast<const float4*>(Wb + (k + 2) * HH + cg);
            float4 w3 = *reinterpret_cast<const float4*>(Wb + (k + 3) * HH + cg);
            acc.x += a.x * w0.x + a.y * w1.x + a.z * w2.x + a.w * w3.x;
            acc.y += a.x * w0.y + a.y * w1.y + a.z * w2.y + a.w * w3.y;
            acc.z += a.x * w0.z + a.y * w1.z + a.z * w2.z + a.w * w3.z;
            acc.w += a.x * w0.w + a.y * w1.w + a.z * w2.w + a.w * w3.w;
        }
        *reinterpret_cast<float4*>(&pp[ks][r][cg]) = acc;
    }
    __syncthreads();
    if (ks == 0) {
        float4 s0 = *reinterpret_cast<const float4*>(&pp[0][r][cg]);
        #pragma unroll
        for (int q = 1; q < 8; ++q) {
            float4 p = *reinterpret_cast<const float4*>(&pp[q][r][cg]);
            s0.x += p.x; s0.y += p.y; s0.z += p.z; s0.w += p.w;
        }
        *reinterpret_cast<float4*>(ei + (row0 + r) * HH + cg) = s0;
    } else if (ks == 8) {
        float4 s0 = *reinterpret_cast<const float4*>(&pp[8][r][cg]);
        #pragma unroll
        for (int q = 9; q < 16; ++q) {
            float4 p = *reinterpret_cast<const float4*>(&pp[q][r][cg]);
            s0.x += p.x; s0.y += p.y; s0.z += p.z; s0.w += p.w;
        }
        float4 bv = *reinterpret_cast<const float4*>(ba1 + cg);
        s0.x += bv.x; s0.y += bv.y; s0.z += bv.z; s0.w += bv.w;
        *reinterpret_cast<float4*>(ejb + (row0 + r) * HH + cg) = s0;
    }
}

// ---------------------------------------------------------------------------
// k2_raw: raw scores, ordered 64x64 tiles. 256 blocks (EXACTLY 1/CU, zero
// tail) x 512 threads. Each thread: 4 rows x 2 cols register block ->
// 7 ds_read_b128 per h-iter for 8 outputs (was 10 for 8).
// Writes raw S into d_out (overwritten by k3_sym).
// ---------------------------------------------------------------------------
__global__ __launch_bounds__(512, 2) void k2_raw(
    const float* __restrict__ ei, const float* __restrict__ ejb,
    const float* __restrict__ wa2, float* __restrict__ sraw)
{
    __shared__ float eil[64][68];
    __shared__ float ejl[64][68];
    __shared__ float wl[64];
    const int tid = threadIdx.x;
    const int i0 = (blockIdx.x >> 4) * 64;
    const int j0 = (blockIdx.x & 15) * 64;

    // stage: 1024 float4 per array, 512 threads -> 2 each
    {
        const int rr = tid >> 4;          // 0..31
        const int cq = (tid & 15) << 2;
        #pragma unroll
        for (int l = 0; l < 2; ++l) {
            int r = rr + 32 * l;
            *reinterpret_cast<float4*>(&eil[r][cq]) =
                *reinterpret_cast<const float4*>(ei + (i0 + r) * HH + cq);
            *reinterpret_cast<float4*>(&ejl[r][cq]) =
                *reinterpret_cast<const float4*>(ejb + (j0 + r) * HH + cq);
        }
    }
    if (tid < 16) {
        *reinterpret_cast<float4*>(&wl[tid * 4]) =
            *reinterpret_cast<const float4*>(wa2 + tid * 4);
    }
    __syncthreads();

    const int ty = tid >> 5;   // 0..15 -> rows ty+16m
    const int tx = tid & 31;   // cols tx and tx+32
    float acc[4][2] = {};

    #pragma unroll 4
    for (int h = 0; h < HH; h += 4) {
        float4 w  = *reinterpret_cast<const float4*>(&wl[h]);
        float4 B0 = *reinterpret_cast<const float4*>(&ejl[tx][h]);
        float4 B1 = *reinterpret_cast<const float4*>(&ejl[tx + 32][h]);
        #pragma unroll
        for (int m = 0; m < 4; ++m) {
            float4 A = *reinterpret_cast<const float4*>(&eil[ty + 16 * m][h]);
            acc[m][0] += fmaxf(A.x + B0.x, 0.f) * w.x
                       + fmaxf(A.y + B0.y, 0.f) * w.y
                       + fmaxf(A.z + B0.z, 0.f) * w.z
                       + fmaxf(A.w + B0.w, 0.f) * w.w;
            acc[m][1] += fmaxf(A.x + B1.x, 0.f) * w.x
                       + fmaxf(A.y + B1.y, 0.f) * w.y
                       + fmaxf(A.z + B1.z, 0.f) * w.z
                       + fmaxf(A.w + B1.w, 0.f) * w.w;
        }
    }
    #pragma unroll
    for (int m = 0; m < 4; ++m) {
        const int row = i0 + ty + 16 * m;
        sraw[row * NN + j0 + tx]      = acc[m][0];
        sraw[row * NN + j0 + tx + 32] = acc[m][1];
    }
}

// ---------------------------------------------------------------------------
// k3_sym: symmetrize + bias/temp + sigmoid, in place on d_out, over 32-tile
// pairs (I<=J). L2-resident, memory-light. Plain-store partial sums.
// 528 blocks x 256 threads.
// ---------------------------------------------------------------------------
__global__ __launch_bounds__(256, 4) void k3_sym(
    float* __restrict__ s, const float* __restrict__ ba2,
    const float* __restrict__ temp, float* __restrict__ partials)
{
    __shared__ float A[32][36];    // raw tile (I,J), later adj stash
    __shared__ float Bt[32][33];   // transposed mirror tile: Bt[r][c]=raw[bj+c][bi+r]
    __shared__ float wsum[4];
    const int tid = threadIdx.x;

    int I = 0, rem = blockIdx.x, rl = 32;
    while (rem >= rl) { rem -= rl; ++I; --rl; }
    const int J = I + rem;
    const int bi = I * 32, bj = J * 32;
    const bool off = (I != J);

    const int rb = tid >> 3;          // 0..31
    const int cb = (tid & 7) << 2;    // 0,4,..28

    {   // stage tile (I,J) rows and mirror tile (J,I) rows (both coalesced)
        *reinterpret_cast<float4*>(&A[rb][cb]) =
            *reinterpret_cast<const float4*>(s + (bi + rb) * NN + bj + cb);
        float4 bv = *reinterpret_cast<const float4*>(s + (bj + rb) * NN + bi + cb);
        Bt[cb + 0][rb] = bv.x;
        Bt[cb + 1][rb] = bv.y;
        Bt[cb + 2][rb] = bv.z;
        Bt[cb + 3][rb] = bv.w;
    }
    __syncthreads();

    const float t = fminf(fmaxf(temp[0], 0.1f), 5.0f);
    const float invt = 1.0f / t;
    const float bb = ba2[0];

    float vals[4];
    float lsum = 0.f;
    #pragma unroll
    for (int e = 0; e < 4; ++e) {
        const int c = cb + e;
        float v = (0.5f * (A[rb][c] + Bt[rb][c]) + bb) * invt;
        float adj = 1.0f / (1.0f + __expf(-v));
        vals[e] = adj;
        lsum += adj;
    }
    __syncthreads();   // all raw reads of A done before overwrite

    {   // write own tile (coalesced float4) and stash adj in A
        float4 o;
        o.x = vals[0]; o.y = vals[1]; o.z = vals[2]; o.w = vals[3];
        *reinterpret_cast<float4*>(s + (bi + rb) * NN + bj + cb) = o;
        A[rb][cb + 0] = vals[0];
        A[rb][cb + 1] = vals[1];
        A[rb][cb + 2] = vals[2];
        A[rb][cb + 3] = vals[3];
    }

    if (off) {
        __syncthreads();
        // mirror tile row rb, cols cb..cb+3: adj(bi+cb+e, bj+rb) = A[cb+e][rb]
        float4 o;
        o.x = A[cb + 0][rb];
        o.y = A[cb + 1][rb];
        o.z = A[cb + 2][rb];
        o.w = A[cb + 3][rb];
        *reinterpret_cast<float4*>(s + (bj + rb) * NN + bi + cb) = o;
        lsum *= 2.0f;
    }

    // deterministic per-block partial: fixed shuffle tree + fixed wave order
    float w = lsum;
    #pragma unroll
    for (int o = 32; o > 0; o >>= 1) w += __shfl_down(w, o);
    if ((tid & 63) == 0) wsum[tid >> 6] = w;
    __syncthreads();
    if (tid == 0) {
        partials[blockIdx.x] = (wsum[0] + wsum[1]) + (wsum[2] + wsum[3]);
    }
}

// ---------------------------------------------------------------------------
// k4_reduce: 1 block, fixed-order deterministic tree over 528 partials.
// ---------------------------------------------------------------------------
__global__ __launch_bounds__(256) void k4_reduce(
    const float* __restrict__ partials, float* __restrict__ out_loss)
{
    __shared__ float wsum[4];
    const int tid = threadIdx.x;
    float v = partials[tid] + partials[tid + 256];
    if (tid < 16) v += partials[tid + 512];
    #pragma unroll
    for (int o = 32; o > 0; o >>= 1) v += __shfl_down(v, o);
    if ((tid & 63) == 0) wsum[tid >> 6] = v;
    __syncthreads();
    if (tid == 0) {
        float tot = (wsum[0] + wsum[1]) + (wsum[2] + wsum[3]);
        *out_loss = 0.01f * tot / (float)(NN * NN);
    }
}

extern "C" void kernel_launch(void* const* d_in, const int* in_sizes, int n_in,
                              void* d_out, int out_size, void* d_ws, size_t ws_size,
                              hipStream_t stream)
{
    const float* x    = (const float*)d_in[0];
    const float* W1   = (const float*)d_in[1];
    const float* b1   = (const float*)d_in[2];
    const float* W2   = (const float*)d_in[3];
    const float* b2   = (const float*)d_in[4];
    const float* Wa1  = (const float*)d_in[5];
    const float* ba1  = (const float*)d_in[6];
    const float* wa2  = (const float*)d_in[7];
    const float* ba2  = (const float*)d_in[8];
    const float* temp = (const float*)d_in[9];
    float* out = (float*)d_out;

    float* ei    = (float*)d_ws;            // N*H floats
    float* ejb   = ei + NN * HH;            // N*H floats
    float* parts = ejb + NN * HH;           // NPAIRS floats

    k1_transform<<<NN / 4, 1024, 0, stream>>>(x, W1, b1, W2, b2, Wa1, ba1, ei, ejb);
    k2_raw<<<256, 512, 0, stream>>>(ei, ejb, wa2, out);
    k3_sym<<<NPAIRS, 256, 0, stream>>>(out, ba2, temp, parts);
    k4_reduce<<<1, 256, 0, stream>>>(parts, out + NN * NN);
}